// Round 1
// baseline (611.647 us; speedup 1.0000x reference)
//
#include <hip/hip_runtime.h>
#include <hip/hip_bf16.h>

typedef __bf16 bf16_t;
typedef bf16_t bf16x8 __attribute__((ext_vector_type(8)));
typedef float f32x4 __attribute__((ext_vector_type(4)));

// ---------------------------------------------------------------------------
// K0: Wg1 [k][e] fp32  ->  Wg1T [e][k] bf16  (32x32 LDS tile transpose)
// ---------------------------------------------------------------------------
__global__ void k_wg1t(const float* __restrict__ Wg1, bf16_t* __restrict__ Wg1T) {
    __shared__ float tile[32][33];
    const int k0 = blockIdx.x * 32;
    const int e0 = blockIdx.y * 32;
    const int tx = threadIdx.x;   // 0..31
    const int ty = threadIdx.y;   // 0..7
    #pragma unroll
    for (int i = 0; i < 32; i += 8)
        tile[ty + i][tx] = Wg1[(k0 + ty + i) * 512 + e0 + tx];
    __syncthreads();
    #pragma unroll
    for (int i = 0; i < 32; i += 8)
        Wg1T[(e0 + ty + i) * 512 + k0 + tx] = (bf16_t)tile[tx][ty + i];
}

// ---------------------------------------------------------------------------
// K1: g[b][e] = C_target[b,:] @ Wg2[:,e] + bias[e]   (grid = B x 2 e-halves)
// ---------------------------------------------------------------------------
__global__ __launch_bounds__(256) void k_gate(const float* __restrict__ Ct,
                                              const float* __restrict__ Wg2,
                                              const float* __restrict__ bias,
                                              float* __restrict__ g) {
    __shared__ float q[512];
    const int b = blockIdx.x;
    const int t = threadIdx.x;
    q[t]       = Ct[b * 512 + t];
    q[t + 256] = Ct[b * 512 + t + 256];
    __syncthreads();
    const int e = (blockIdx.y << 8) + t;
    float acc = bias[e];
    #pragma unroll 8
    for (int k = 0; k < 512; ++k)
        acc = fmaf(q[k], Wg2[k * 512 + e], acc);
    g[b * 512 + e] = acc;
}

// ---------------------------------------------------------------------------
// K1b: per-batch compaction of unmasked row indices (ballot prefix).
// Masked rows (~50%) have score = -1e30 independent of the GEMM -> skip them
// entirely in k_score. grid 256 x 64 thr (1 wave).
// ---------------------------------------------------------------------------
__global__ __launch_bounds__(64) void k_compact(const int* __restrict__ mask,
                                                int* __restrict__ idx,
                                                int* __restrict__ nnz) {
    const int b    = blockIdx.x;
    const int lane = threadIdx.x;
    int base = 0;
    #pragma unroll
    for (int c = 0; c < 8; ++c) {
        const int l = (c << 6) + lane;
        const int v = mask[(b << 9) + l];
        const unsigned long long m = __ballot(v != 0);
        const int rank = __popcll(m & ((1ull << lane) - 1ull));
        if (v) idx[(b << 9) + base + rank] = l;
        base += __popcll(m);
    }
    if (lane == 0) nnz[b] = base;
}

// ---------------------------------------------------------------------------
// K2: compacted-row GEMM + fused relu/w0 reduction epilogue.
//   score[l] += sum_{e in half} relu( (C[l,:] @ Wg1)[e] + g[b,e] ) * w0[e]
// Tile: 64 compacted rows x 256 cols (n-half = bid&1, so the pair of blocks
// sharing the same C rows are dispatch-adjacent -> L2 hit on the 2nd read).
// acc[4][4] = 64 AGPR (vs 128 before) -> ~165 unified regs -> 3 waves/SIMD.
// LDS 21.25 KB. A rows prefetched one chunk ahead into registers so the
// cvt+ds_write at phase start has no exposed load latency.
// Two partial sums per row combined with atomicAdd (score pre-zeroed;
// exactly 2 addends -> deterministic). Mask applied later in k_entmax.
// ---------------------------------------------------------------------------
__global__ __launch_bounds__(256, 3) void k_score(const float* __restrict__ C,
                                                  const bf16_t* __restrict__ Wg1T,
                                                  const float* __restrict__ g,
                                                  const float* __restrict__ Wg0,
                                                  const int* __restrict__ idx,
                                                  const int* __restrict__ nnz,
                                                  float* __restrict__ score) {
    __shared__ bf16_t As[64 * 32];      //  4 KB
    __shared__ bf16_t Bs[256 * 32];     // 16 KB
    __shared__ float  sred[4][64];      //  1 KB
    __shared__ int    rs[64];           // 256 B

    const int t    = threadIdx.x;
    const int lane = t & 63;
    const int wave = t >> 6;
    const int quad = lane >> 4;
    const int l15  = lane & 15;

    const int bid  = blockIdx.x;        // 4096 = 256 b x 8 tiles x 2 n-halves
    const int nh   = bid & 1;
    const int tl   = bid >> 1;
    const int b    = tl >> 3;
    const int tile = tl & 7;
    const int nb   = nnz[b];
    if (tile * 64 >= nb) return;        // uniform early exit (no barriers yet)

    if (t < 64) {
        const int j = tile * 64 + t;
        rs[t] = idx[(b << 9) + (j < nb ? j : nb - 1)];   // clamp: dup rows ok
    }
    __syncthreads();

    // per-thread A staging slots: 2 float4 per chunk, fixed rows r0/r1
    const int r0 = t >> 3,        c0 = (t & 7) << 2;
    const int r1 = 32 + (t >> 3);
    const float* Cb  = C + ((size_t)b << 18);
    const float* pa0 = Cb + (size_t)rs[r0] * 512 + c0;
    const float* pa1 = Cb + (size_t)rs[r1] * 512 + c0;

    float4 va0 = *reinterpret_cast<const float4*>(pa0);   // kc=0 prefetch
    float4 va1 = *reinterpret_cast<const float4*>(pa1);

    const int ncol0 = nh << 8;
    f32x4 acc[4][4] = {};

    for (int kc = 0; kc < 512; kc += 32) {
        __syncthreads();
        // ---- stage B: 256 n x 32 k of Wg1T, async DMA straight to LDS ----
        #pragma unroll
        for (int i = 0; i < 4; ++i) {
            const int f  = i * 256 + t;        // 0..1023 16-B slots
            const int r  = f >> 2;
            const int c8 = (f & 3) << 3;
            __builtin_amdgcn_global_load_lds(
                (const __attribute__((address_space(1))) void*)(Wg1T + (size_t)(ncol0 + r) * 512 + kc + c8),
                (__attribute__((address_space(3))) void*)(Bs + f * 8), 16, 0, 0);
        }
        // ---- stage A: write last chunk's prefetched regs, issue next ----
        {
            union { bf16_t h[4]; uint2 u; } pk;
            pk.h[0] = (bf16_t)va0.x; pk.h[1] = (bf16_t)va0.y;
            pk.h[2] = (bf16_t)va0.z; pk.h[3] = (bf16_t)va0.w;
            *reinterpret_cast<uint2*>(&As[r0 * 32 + c0]) = pk.u;
            pk.h[0] = (bf16_t)va1.x; pk.h[1] = (bf16_t)va1.y;
            pk.h[2] = (bf16_t)va1.z; pk.h[3] = (bf16_t)va1.w;
            *reinterpret_cast<uint2*>(&As[r1 * 32 + c0]) = pk.u;
        }
        if (kc + 32 < 512) {
            va0 = *reinterpret_cast<const float4*>(pa0 + kc + 32);
            va1 = *reinterpret_cast<const float4*>(pa1 + kc + 32);
        }
        __syncthreads();
        // ---- fragments + 16 MFMA ----
        bf16x8 afr[4], bfr[4];
        #pragma unroll
        for (int mi = 0; mi < 4; ++mi)
            afr[mi] = *reinterpret_cast<const bf16x8*>(
                &As[(mi * 16 + l15) * 32 + quad * 8]);
        #pragma unroll
        for (int ni = 0; ni < 4; ++ni)
            bfr[ni] = *reinterpret_cast<const bf16x8*>(
                &Bs[(wave * 64 + ni * 16 + l15) * 32 + quad * 8]);
        #pragma unroll
        for (int mi = 0; mi < 4; ++mi)
            #pragma unroll
            for (int ni = 0; ni < 4; ++ni)
                acc[mi][ni] = __builtin_amdgcn_mfma_f32_16x16x32_bf16(
                    afr[mi], bfr[ni], acc[mi][ni], 0, 0, 0);
    }

    // ---- epilogue: relu(u+g)*w0, reduce over this block's 256 n ----
    float rsum[16];
    #pragma unroll
    for (int i = 0; i < 16; ++i) rsum[i] = 0.f;
    #pragma unroll
    for (int ni = 0; ni < 4; ++ni) {
        const int n  = ncol0 + wave * 64 + ni * 16 + l15;   // D col = lane&15
        const float gv = g[(b << 9) + n];
        const float w0 = Wg0[n];
        #pragma unroll
        for (int mi = 0; mi < 4; ++mi)
            #pragma unroll
            for (int r = 0; r < 4; ++r) {            // D row = quad*4 + r
                const float u = fmaxf(acc[mi][ni][r] + gv, 0.f);
                rsum[mi * 4 + r] = fmaf(u, w0, rsum[mi * 4 + r]);
            }
    }
    #pragma unroll
    for (int i = 0; i < 16; ++i) {
        float v = rsum[i];
        v += __shfl_xor(v, 1);
        v += __shfl_xor(v, 2);
        v += __shfl_xor(v, 4);
        v += __shfl_xor(v, 8);
        rsum[i] = v;
    }
    if (l15 == 0) {
        #pragma unroll
        for (int mi = 0; mi < 4; ++mi)
            #pragma unroll
            for (int r = 0; r < 4; ++r)
                sred[wave][mi * 16 + quad * 4 + r] = rsum[mi * 4 + r];
    }
    __syncthreads();
    if (t < 64) {
        const float sc = sred[0][t] + sred[1][t] + sred[2][t] + sred[3][t];
        if (tile * 64 + t < nb)
            atomicAdd(&score[(b << 9) + rs[t]], sc);
    }
}

// ---------------------------------------------------------------------------
// K3: entmax bisection — one wave per batch, 256 blocks (full chip), no
// barriers, x^2 fast path. Applies the mask itself (masked score slots are
// garbage from k_score-skip) and emits the COMPACTED support (idx,val,count)
// so k_attn only touches rows with p > 0.
// ---------------------------------------------------------------------------
__global__ __launch_bounds__(64) void k_entmax(const float* __restrict__ score,
                                               const int* __restrict__ mask,
                                               const float* __restrict__ alpha,
                                               int* __restrict__ sidx,
                                               float* __restrict__ sval,
                                               int* __restrict__ snnz) {
    const int lane = threadIdx.x;
    const int b    = blockIdx.x;
    const float am1 = alpha[0] - 1.0f;
    const float inv = 1.0f / am1;
    const bool  sq  = fabsf(inv - 2.0f) < 1e-6f;   // alpha==1.5 -> u*u
    const float neg = -1e30f * am1;

    const float* sb = score + (b << 9);
    const int*   mb = mask  + (b << 9);
    float x[8];
    {
        const float4 v0 = *reinterpret_cast<const float4*>(sb + lane * 8);
        const float4 v1 = *reinterpret_cast<const float4*>(sb + lane * 8 + 4);
        const int4   m0 = *reinterpret_cast<const int4*>(mb + lane * 8);
        const int4   m1 = *reinterpret_cast<const int4*>(mb + lane * 8 + 4);
        x[0] = m0.x ? v0.x * am1 : neg; x[1] = m0.y ? v0.y * am1 : neg;
        x[2] = m0.z ? v0.z * am1 : neg; x[3] = m0.w ? v0.w * am1 : neg;
        x[4] = m1.x ? v1.x * am1 : neg; x[5] = m1.y ? v1.y * am1 : neg;
        x[6] = m1.z ? v1.z * am1 : neg; x[7] = m1.w ? v1.w * am1 : neg;
    }
    float m = x[0];
    #pragma unroll
    for (int j = 1; j < 8; ++j) m = fmaxf(m, x[j]);
    #pragma unroll
    for (int s = 1; s < 64; s <<= 1) m = fmaxf(m, __shfl_xor(m, s));

    float tau_lo = m - 1.0f;
    float dm = (m - powf(1.0f / 512.0f, am1)) - tau_lo;

    float f_lo;
    {
        float s = 0.f;
        #pragma unroll
        for (int j = 0; j < 8; ++j) {
            const float u = fmaxf(x[j] - tau_lo, 0.f);
            s += sq ? u * u : powf(u, inv);
        }
        #pragma unroll
        for (int sh = 1; sh < 64; sh <<= 1) s += __shfl_xor(s, sh);
        f_lo = s - 1.0f;
    }
    for (int it = 0; it < 50; ++it) {
        dm *= 0.5f;
        const float tau_m = tau_lo + dm;
        float s = 0.f;
        #pragma unroll
        for (int j = 0; j < 8; ++j) {
            const float u = fmaxf(x[j] - tau_m, 0.f);
            s += sq ? u * u : powf(u, inv);
        }
        #pragma unroll
        for (int sh = 1; sh < 64; sh <<= 1) s += __shfl_xor(s, sh);
        if ((s - 1.0f) * f_lo >= 0.f) tau_lo = tau_m;
    }
    const float tau = tau_lo + 0.5f * dm;
    float pj[8];
    float Z = 0.f;
    #pragma unroll
    for (int j = 0; j < 8; ++j) {
        const float u = fmaxf(x[j] - tau, 0.f);
        pj[j] = sq ? u * u : powf(u, inv);
        Z += pj[j];
    }
    #pragma unroll
    for (int sh = 1; sh < 64; sh <<= 1) Z += __shfl_xor(Z, sh);
    const float rz = 1.0f / Z;

    // ---- ballot-compact the support ----
    int base = 0;
    #pragma unroll
    for (int j = 0; j < 8; ++j) {
        const float pv = pj[j] * rz;
        const unsigned long long bm = __ballot(pv > 0.f);
        const int rank = __popcll(bm & ((1ull << lane) - 1ull));
        if (pv > 0.f) {
            sidx[(b << 9) + base + rank] = lane * 8 + j;
            sval[(b << 9) + base + rank] = pv;
        }
        base += __popcll(bm);
    }
    if (lane == 0) snnz[b] = base;
}

// ---------------------------------------------------------------------------
// K4: attn[b][e] = sum_{j in support} pval[j] * C[b, pidx[j], e].
// Branch-free unroll-8 over the compacted support (coeffs staged in LDS)
// -> 8 independent HBM loads in flight per wave. grid (256 b, 2 e-halves).
// ---------------------------------------------------------------------------
__global__ __launch_bounds__(256) void k_attn(const int* __restrict__ sidx,
                                              const float* __restrict__ sval,
                                              const int* __restrict__ snnz,
                                              const float* __restrict__ C,
                                              float* __restrict__ attn) {
    __shared__ int   li[512];
    __shared__ float lv[512];
    const int b = blockIdx.x;
    const int t = threadIdx.x;
    const int e = (blockIdx.y << 8) + t;
    const int n = snnz[b];
    for (int i = t; i < n; i += 256) {
        li[i] = sidx[(b << 9) + i];
        lv[i] = sval[(b << 9) + i];
    }
    __syncthreads();
    const float* Cb = C + ((size_t)b << 18);
    float a = 0.f;
    int j = 0;
    for (; j + 8 <= n; j += 8) {
        #pragma unroll
        for (int u = 0; u < 8; ++u)
            a = fmaf(lv[j + u], Cb[((size_t)li[j + u] << 9) + e], a);
    }
    for (; j < n; ++j)
        a = fmaf(lv[j], Cb[((size_t)li[j] << 9) + e], a);
    attn[(b << 9) + e] = a;
}

// ---------------------------------------------------------------------------
// K5: out[b][d] += sum_{e in chunk} attn[b][e] * X[b][e][d].
// grid (256, 4 e-chunks), atomicAdd epilogue (out pre-zeroed).
// ---------------------------------------------------------------------------
__global__ __launch_bounds__(256) void k_out(const float* __restrict__ attn,
                                             const float* __restrict__ X,
                                             float* __restrict__ out) {
    __shared__ float as_[128];
    const int b  = blockIdx.x;
    const int ec = blockIdx.y;
    const int t  = threadIdx.x;
    if (t < 128) as_[t] = attn[(b << 9) + (ec << 7) + t];
    __syncthreads();
    const float* Xb = X + (size_t)b * 512 * 256 + (size_t)(ec << 7) * 256;
    float acc = 0.f;
    #pragma unroll 8
    for (int e = 0; e < 128; ++e)
        acc = fmaf(as_[e], Xb[e * 256 + t], acc);
    atomicAdd(&out[(b << 8) + t], acc);
}

// ---------------------------------------------------------------------------
extern "C" void kernel_launch(void* const* d_in, const int* in_sizes, int n_in,
                              void* d_out, int out_size, void* d_ws, size_t ws_size,
                              hipStream_t stream) {
    const float* C_target = (const float*)d_in[0];
    const float* C        = (const float*)d_in[1];
    const float* X        = (const float*)d_in[2];
    const float* alpha    = (const float*)d_in[3];
    const int*   mask     = (const int*)  d_in[4];
    const float* Wg1      = (const float*)d_in[5];
    const float* Wg2      = (const float*)d_in[6];
    const float* Wg0      = (const float*)d_in[7];
    const float* bias     = (const float*)d_in[8];
    float* out = (float*)d_out;

    char* ws = (char*)d_ws;
    bf16_t* wg1t  = (bf16_t*)(ws);                       // 512 KB
    float*  g     = (float*)(ws + ( 512u << 10));        // 512 KB
    float*  score = (float*)(ws + (1024u << 10));        // 512 KB
    int*    idx   = (int*)  (ws + (1536u << 10));        // 512 KB
    int*    sidx  = (int*)  (ws + (2048u << 10));        // 512 KB
    float*  sval  = (float*)(ws + (2560u << 10));        // 512 KB
    float*  attn  = (float*)(ws + (3072u << 10));        // 512 KB
    int*    nnz   = (int*)  (ws + (3584u << 10));        //   1 KB
    int*    snnz  = (int*)  (ws + (3584u << 10) + 4096); //   1 KB

    k_wg1t   <<<dim3(16, 16), dim3(32, 8), 0, stream>>>(Wg1, wg1t);
    k_gate   <<<dim3(256, 2), 256, 0, stream>>>(C_target, Wg2, bias, g);
    k_compact<<<256, 64, 0, stream>>>(mask, idx, nnz);
    hipMemsetAsync(score, 0, 512u << 10, stream);
    k_score  <<<4096, 256, 0, stream>>>(C, wg1t, g, Wg0, idx, nnz, score);
    k_entmax <<<256, 64, 0, stream>>>(score, mask, alpha, sidx, sval, snnz);
    k_attn   <<<dim3(256, 2), 256, 0, stream>>>(sidx, sval, snnz, C, attn);
    hipMemsetAsync(d_out, 0, (size_t)out_size * sizeof(float), stream);
    k_out    <<<dim3(256, 4), 256, 0, stream>>>(attn, X, out);
}